// Round 11
// baseline (151.543 us; speedup 1.0000x reference)
//
#include <hip/hip_runtime.h>

typedef short s16x8 __attribute__((ext_vector_type(8)));
typedef float f32x4 __attribute__((ext_vector_type(4)));
typedef float f32x16 __attribute__((ext_vector_type(16)));
typedef unsigned int u32x4 __attribute__((ext_vector_type(4)));

__device__ __forceinline__ unsigned short f2bf(float f) {
    unsigned int u = __float_as_uint(f);
    u += 0x7fff + ((u >> 16) & 1);   // RNE
    return (unsigned short)(u >> 16);
}
__device__ __forceinline__ float bf2f(unsigned short h) {
    return __uint_as_float(((unsigned int)h) << 16);
}
__device__ __forceinline__ unsigned pack2bf(float lo, float hi) {
    return (unsigned)f2bf(lo) | ((unsigned)f2bf(hi) << 16);   // RNE both halves
}
__device__ __forceinline__ f32x4 mfma16(s16x8 a, s16x8 b, f32x4 c) {
    return __builtin_amdgcn_mfma_f32_16x16x32_bf16(a, b, c, 0, 0, 0);
}
__device__ __forceinline__ f32x16 mfma32(s16x8 a, s16x8 b, f32x16 c) {
    return __builtin_amdgcn_mfma_f32_32x32x16_bf16(a, b, c, 0, 0, 0);
}
__device__ __forceinline__ void async16(const void* g, void* l) {
    __builtin_amdgcn_global_load_lds(
        (const __attribute__((address_space(1))) void*)g,
        (__attribute__((address_space(3))) void*)l, 16, 0, 0);
}

#define ROPE_C (-13.287712379549449f / 32.0f)

// ---------------------------------------------------------------------------
// fp32 -> bf16: x -> xb, wq|wk|wv -> wqkvb, wp -> wpb.
// ---------------------------------------------------------------------------
__global__ __launch_bounds__(256) void convert_all(
    const float* __restrict__ x,  const float* __restrict__ wq,
    const float* __restrict__ wk, const float* __restrict__ wv,
    const float* __restrict__ wp,
    unsigned short* __restrict__ xb, unsigned short* __restrict__ wqkvb,
    unsigned short* __restrict__ wpb)
{
    const size_t XN = 2048u * 1024u, WN = 1024u * 1024u;
    size_t e = ((size_t)blockIdx.x * 256 + threadIdx.x) * 4;
    const float* s; unsigned short* d;
    if (e < XN)                { s = x  + e;               d = xb    + e; }
    else if (e < XN + WN)      { s = wq + (e - XN);        d = wqkvb + (e - XN); }
    else if (e < XN + 2 * WN)  { s = wk + (e - XN - WN);   d = wqkvb + (e - XN); }
    else if (e < XN + 3 * WN)  { s = wv + (e - XN - 2*WN); d = wqkvb + (e - XN); }
    else                       { s = wp + (e - XN - 3*WN); d = wpb   + (e - XN - 3*WN); }
    float4 v = *(const float4*)s;
    ushort4 o;
    o.x = f2bf(v.x); o.y = f2bf(v.y); o.z = f2bf(v.z); o.w = f2bf(v.w);
    *(ushort4*)d = o;
}

// ---------------------------------------------------------------------------
// bf16 GEMM (m97 structure, BK=64): C = A[M x 1024] * B[N x 1024]^T.
// BM x BN tile, 4 waves (2x2), wave tile (BM/2)x(BN/2), global_load_lds.
//
// R11: 1D grid with XCD-aware decode (T1 — same mechanism that fixed attn
// in R8). GX columns of blocks, 32 rows; XCD = bid&7 owns the contiguous
// bx-strip [xcd*CX, xcd*CX+CX), CX = GX/8. B-panel per XCD: qkv 768KB /
// proj 256KB -> L2-resident; A (~4MB) ~ one L2. Bijective decode:
//   bx = (bid&7)*CX + (bid>>3)%CX ; by = (bid>>3)/CX.
//
// *** RoPE binding order IS CORRECT AS WRITTEN — do not "fix" it. ***
// __sincosf(ang,&c,&s) binds c=sin(ang), s=cos(ang); the update is
// R(theta - pi/2) — reference rotation composed with a CONSTANT 90-degree
// rotation. Applied identically to q and k, the relative rotation
// R(th_n - th_m) (all logits see) matches the reference exactly.
// Binding sin-first gives the INVERSE relative rotation (R4 fail, 2.9e-2).
//
// Q-prescale: q section (n0<1024) scaled by 0.125 = 2^-3 (exact in bf16 ->
// attn exp argument BIT-IDENTICAL); removes *0.125f from attn hot loop.
// (R9/R10 note: transposed-V epilogue FAILED twice (2e-3/5e-3) despite
// audits — abandoned; v section is written normally into qkv.)
//
// NOTE (R3): 128x128 tile at this shape starves the grid (384 blocks,
// occ 7.3%, 57us) — 64x128 (768 blocks) is right here.
// ---------------------------------------------------------------------------
template<int BM, int BN, int C32, int ROPE, int GX>
__global__ __launch_bounds__(256) void gemm_mfma(
    const unsigned short* __restrict__ A,
    const unsigned short* __restrict__ B,
    void* __restrict__ C, int Ntot)
{
    constexpr int MT = BM / 32, NT = BN / 32;
    constexpr int CX = GX / 8;
    __shared__ unsigned short As[BM * 64];
    __shared__ unsigned short Bs[BN * 64];

    const int bid  = blockIdx.x;
    const int bx   = (bid & 7) * CX + ((bid >> 3) % CX);
    const int by   = (bid >> 3) / CX;

    const int tid  = threadIdx.x;
    const int wave = tid >> 6, lane = tid & 63;
    const int l16  = lane & 15, quad = lane >> 4;
    const int m0   = by * BM, n0 = bx * BN;
    const int wm   = (wave & 1) * (BM / 2), wn = (wave >> 1) * (BN / 2);

    const int srow8 = lane >> 3;        // 0..7
    const int scol  = (lane & 7) * 8;   // 0..56

    f32x4 acc[MT][NT] = {};

    for (int k0 = 0; k0 < 1024; k0 += 64) {
        #pragma unroll
        for (int i = 0; i < BM / 32; i++) {
            int j = wave * (BM / 32) + i;
            async16(A + (size_t)(m0 + j * 8 + srow8) * 1024 + k0 + scol, &As[j * 512]);
        }
        #pragma unroll
        for (int i = 0; i < BN / 32; i++) {
            int j = wave * (BN / 32) + i;
            async16(B + (size_t)(n0 + j * 8 + srow8) * 1024 + k0 + scol, &Bs[j * 512]);
        }
        __syncthreads();

        #pragma unroll
        for (int ks = 0; ks < 2; ks++) {
            s16x8 af[MT], bfr[NT];
            #pragma unroll
            for (int mt = 0; mt < MT; mt++)
                af[mt] = *(const s16x8*)&As[(wm + mt * 16 + l16) * 64 + ks * 32 + quad * 8];
            #pragma unroll
            for (int nt = 0; nt < NT; nt++)
                bfr[nt] = *(const s16x8*)&Bs[(wn + nt * 16 + l16) * 64 + ks * 32 + quad * 8];
            #pragma unroll
            for (int mt = 0; mt < MT; mt++)
                #pragma unroll
                for (int nt = 0; nt < NT; nt++)
                    acc[mt][nt] = mfma16(af[mt], bfr[nt], acc[mt][nt]);
        }
        __syncthreads();
    }

    // Fused RoPE on q/k sections (in-register, fp32, before bf16 store)
    if constexpr (ROPE) {
        if (n0 < 2048) {
            const float sc = (n0 < 1024) ? 0.125f : 1.0f;   // Q-prescale
            #pragma unroll
            for (int mt = 0; mt < MT; mt++)
                #pragma unroll
                for (int r = 0; r < 4; r++) {
                    int m = m0 + wm + mt * 16 + quad * 4 + r;   // token
                    #pragma unroll
                    for (int nt = 0; nt < 2; nt++) {
                        int i = nt * 16 + l16;                  // 0..31 in head
                        float ang = (float)m * exp2f((float)i * ROPE_C);
                        float c, s;
                        __sincosf(ang, &c, &s);   // c=sin, s=cos — see header note
                        c *= sc; s *= sc;
                        float e0 = acc[mt][nt][r], e1 = acc[mt][nt + 2][r];
                        acc[mt][nt][r]     = e0 * c + e1 * s;
                        acc[mt][nt + 2][r] = e1 * c - e0 * s;
                    }
                }
        }
    }

    // C/D layout: col = lane&15, row = quad*4 + reg
    #pragma unroll
    for (int mt = 0; mt < MT; mt++)
        #pragma unroll
        for (int nt = 0; nt < NT; nt++)
            #pragma unroll
            for (int r = 0; r < 4; r++) {
                int m = m0 + wm + mt * 16 + quad * 4 + r;
                int n = n0 + wn + nt * 16 + l16;
                size_t idx = (size_t)m * Ntot + n;
                if (C32) ((float*)C)[idx] = acc[mt][nt][r];
                else     ((unsigned short*)C)[idx] = f2bf(acc[mt][nt][r]);
            }
}

// ---------------------------------------------------------------------------
// Split-K flash attention, 32x32x16 MFMA, operand-swapped QK (verified r12).
// 1024 blocks, XCD-swizzled 1D grid (R8-proven: FETCH 70MB->~15MB, 3x):
//   16 q-blocks sharing one (head,ksplit) slice get ids congruent mod 8 ->
//   same XCD -> per-XCD L2 working set ~1MB << 4MB.
// Body = R8-passing loop (pad-72 LDS, single buffer, two barriers,
// reg->LDS staging; V gathered+transposed from qkv) + T5 s_setprio around
// MFMA clusters (4 independent blocks/CU at different phases -> scheduler
// can favor the MFMA-issuing wave; m191 +4-7%).
//
// P never touches LDS (T12): pack RNE pairs, v_permlane32_swap_b32
// (dst[32:63]<->src[0:31]): swap(lo,hi) -> lo'=word0/1, hi'=word2/3.
// Conversion must stay f2bf RNE (cvt_pk truncates -> 8e-3 bias, R2 fail).
// Q pre-scaled by 0.125 in qkv GEMM.
// ---------------------------------------------------------------------------
__global__ __launch_bounds__(256, 4) void attn_part(
    const unsigned short* __restrict__ qkv,
    unsigned short* __restrict__ Opart, float* __restrict__ Lpart)
{
    const int bid    = blockIdx.x;
    const int member = (bid >> 3) & 15;
    const int slice  = (bid & 7) + 8 * (bid >> 7);
    const int h  = slice & 15;
    const int ks = slice >> 4;
    const int q0 = member * 128;

    const int tid  = threadIdx.x;
    const int wave = tid >> 6, lane = tid & 63;
    const int l32  = lane & 31, half = lane >> 5;

    __shared__ unsigned short Ks[64][72];      // [key][d]
    __shared__ unsigned short Vt[64][72];      // [d][key]

    const unsigned short* qp = qkv + (size_t)(q0 + wave * 32 + l32) * 3072 + h * 64 + half * 8;
    s16x8 qb[4];
    #pragma unroll
    for (int c = 0; c < 4; c++)
        qb[c] = *(const s16x8*)(qp + c * 16);

    f32x16 o0 = {}, o1 = {};
    float lsum = 0.f;

    for (int t = 0; t < 8; t++) {
        const int kt = ks * 512 + t * 64;

        if (tid < 128) {
            int g  = tid & 15;
            int d0 = (tid >> 4) * 8;
            const unsigned short* gv = qkv + (size_t)(kt + 4 * g) * 3072 + 2048 + h * 64 + d0;
            unsigned short a0[8], a1[8], a2[8], a3[8];
            *(uint4*)a0 = *(const uint4*)gv;
            *(uint4*)a1 = *(const uint4*)(gv + 3072);
            *(uint4*)a2 = *(const uint4*)(gv + 6144);
            *(uint4*)a3 = *(const uint4*)(gv + 9216);
            #pragma unroll
            for (int d = 0; d < 8; d++) {
                ushort4 w;
                w.x = a0[d]; w.y = a1[d]; w.z = a2[d]; w.w = a3[d];
                *(ushort4*)&Vt[d0 + d][4 * g] = w;
            }
        } else {
            int u = tid - 128;
            int key = u & 63;
            int dh = (u >> 6) * 32;
            const unsigned short* gk = qkv + (size_t)(kt + key) * 3072 + 1024 + h * 64 + dh;
            const uint4* g4 = (const uint4*)gk;
            uint4 k0 = g4[0], k1 = g4[1], k2 = g4[2], k3 = g4[3];
            *(uint4*)&Ks[key][dh]      = k0;
            *(uint4*)&Ks[key][dh + 8]  = k1;
            *(uint4*)&Ks[key][dh + 16] = k2;
            *(uint4*)&Ks[key][dh + 24] = k3;
        }
        __syncthreads();

        #pragma unroll
        for (int g = 0; g < 2; g++) {
            f32x16 s = {};
            __builtin_amdgcn_s_setprio(1);
            #pragma unroll
            for (int c = 0; c < 4; c++) {
                s16x8 ka = *(const s16x8*)&Ks[g * 32 + l32][c * 16 + half * 8];
                s = mfma32(ka, qb[c], s);
            }
            __builtin_amdgcn_s_setprio(0);
            #pragma unroll
            for (int f = 0; f < 2; f++) {
                float e[8];
                #pragma unroll
                for (int j = 0; j < 8; j++) {
                    e[j] = __expf(s[8 * f + j]);   // scale folded into Q
                    lsum += e[j];
                }
                // RNE-packed pairs (bit-identical P to LDS baseline)
                unsigned w0 = pack2bf(e[0], e[1]);   // lo0
                unsigned w1 = pack2bf(e[2], e[3]);   // lo1
                unsigned w2 = pack2bf(e[4], e[5]);   // hi0
                unsigned w3 = pack2bf(e[6], e[7]);   // hi1
                // DST=lo, SRC=hi: dst'=word0/1, src'=word2/3
                asm("v_permlane32_swap_b32 %0, %1" : "+v"(w0), "+v"(w2));
                asm("v_permlane32_swap_b32 %0, %1" : "+v"(w1), "+v"(w3));
                u32x4 wv; wv.x = w0; wv.y = w1; wv.z = w2; wv.w = w3;
                s16x8 pa = __builtin_bit_cast(s16x8, wv);
                const int c = 2 * g + f;
                s16x8 v0 = *(const s16x8*)&Vt[l32][c * 16 + half * 8];
                s16x8 v1 = *(const s16x8*)&Vt[32 + l32][c * 16 + half * 8];
                __builtin_amdgcn_s_setprio(1);
                o0 = mfma32(pa, v0, o0);
                o1 = mfma32(pa, v1, o1);
                __builtin_amdgcn_s_setprio(0);
            }
        }
        __syncthreads();
    }

    lsum += __shfl_xor(lsum, 32, 64);

    const int mq = q0 + wave * 32;
    unsigned short* opBase = Opart + (size_t)ks * 2048 * 1024;
    #pragma unroll
    for (int r = 0; r < 16; r++) {
        int qr = (r & 3) + 8 * (r >> 2) + 4 * half;
        unsigned short* op = opBase + (size_t)(mq + qr) * 1024 + h * 64;
        op[l32]      = f2bf(o0[r]);
        op[32 + l32] = f2bf(o1[r]);
    }
    if (half == 0)
        Lpart[((size_t)ks * 2048 + mq + l32) * 16 + h] = lsum;
}

// ---------------------------------------------------------------------------
// Combine 4 bf16 split-K partials: ab = (sum n_i) / (sum l_i), bf16.
// ---------------------------------------------------------------------------
__global__ __launch_bounds__(256) void combine(
    const unsigned short* __restrict__ Opart, const float* __restrict__ Lpart,
    unsigned short* __restrict__ ab)
{
    size_t e = ((size_t)blockIdx.x * 256 + threadIdx.x) * 4;
    int tok = (int)(e >> 10);
    int h = (int)((e & 1023) >> 6);
    float l = 0.f;
    #pragma unroll
    for (int s = 0; s < 4; s++)
        l += Lpart[((size_t)s * 2048 + tok) * 16 + h];
    float inv = 1.0f / l;
    float a0 = 0.f, a1 = 0.f, a2 = 0.f, a3 = 0.f;
    #pragma unroll
    for (int s = 0; s < 4; s++) {
        ushort4 n = *(const ushort4*)(Opart + (size_t)s * 2048 * 1024 + e);
        a0 += bf2f(n.x); a1 += bf2f(n.y); a2 += bf2f(n.z); a3 += bf2f(n.w);
    }
    ushort4 w;
    w.x = f2bf(a0 * inv);
    w.y = f2bf(a1 * inv);
    w.z = f2bf(a2 * inv);
    w.w = f2bf(a3 * inv);
    *(ushort4*)(ab + e) = w;
}

extern "C" void kernel_launch(void* const* d_in, const int* in_sizes, int n_in,
                              void* d_out, int out_size, void* d_ws, size_t ws_size,
                              hipStream_t stream)
{
    const float* x  = (const float*)d_in[0];
    const float* wq = (const float*)d_in[1];
    const float* wk = (const float*)d_in[2];
    const float* wv = (const float*)d_in[3];
    const float* wp = (const float*)d_in[4];

    unsigned short* xb    = (unsigned short*)d_ws;        // 2M shorts
    unsigned short* wqkvb = xb    + 2u * 1024 * 1024;     // 3M
    unsigned short* wpb   = wqkvb + 3u * 1024 * 1024;     // 1M
    unsigned short* qkv   = wpb   + 1u * 1024 * 1024;     // 6M
    unsigned short* ab    = qkv   + 2048u * 3072;         // 2M
    unsigned short* Opart = ab    + 2u * 1024 * 1024;     // 4 x 2048 x 1024 bf16
    float* Lpart = (float*)(Opart + 4u * 2048 * 1024);    // 4 x 2048 x 16 fp32

    convert_all<<<6144, 256, 0, stream>>>(x, wq, wk, wv, wp, xb, wqkvb, wpb);
    // qkv GEMM with fused RoPE: 64x128 tile, 1D XCD-swizzled grid of 768
    gemm_mfma<64, 128, 0, 1, 24><<<768, 256, 0, stream>>>(
        xb, wqkvb, qkv, 3072);
    // attn: 1D XCD-swizzled grid (R8 body + setprio)
    attn_part<<<1024, 256, 0, stream>>>(qkv, Opart, Lpart);
    combine<<<2048, 256, 0, stream>>>(Opart, Lpart, ab);
    // proj: 64x64 tile, 1D XCD-swizzled grid of 512, fp32 out
    gemm_mfma<64, 64, 1, 0, 16><<<512, 256, 0, stream>>>(
        ab, wpb, d_out, 1024);
}

// Round 12
// 150.316 us; speedup vs baseline: 1.0082x; 1.0082x over previous
//
#include <hip/hip_runtime.h>

typedef short s16x8 __attribute__((ext_vector_type(8)));
typedef float f32x4 __attribute__((ext_vector_type(4)));
typedef float f32x16 __attribute__((ext_vector_type(16)));
typedef unsigned int u32x4 __attribute__((ext_vector_type(4)));

__device__ __forceinline__ unsigned short f2bf(float f) {
    unsigned int u = __float_as_uint(f);
    u += 0x7fff + ((u >> 16) & 1);   // RNE
    return (unsigned short)(u >> 16);
}
__device__ __forceinline__ float bf2f(unsigned short h) {
    return __uint_as_float(((unsigned int)h) << 16);
}
__device__ __forceinline__ unsigned pack2bf(float lo, float hi) {
    return (unsigned)f2bf(lo) | ((unsigned)f2bf(hi) << 16);   // RNE both halves
}
__device__ __forceinline__ f32x4 mfma16(s16x8 a, s16x8 b, f32x4 c) {
    return __builtin_amdgcn_mfma_f32_16x16x32_bf16(a, b, c, 0, 0, 0);
}
__device__ __forceinline__ f32x16 mfma32(s16x8 a, s16x8 b, f32x16 c) {
    return __builtin_amdgcn_mfma_f32_32x32x16_bf16(a, b, c, 0, 0, 0);
}
__device__ __forceinline__ void async16(const void* g, void* l) {
    __builtin_amdgcn_global_load_lds(
        (const __attribute__((address_space(1))) void*)g,
        (__attribute__((address_space(3))) void*)l, 16, 0, 0);
}

#define ROPE_C (-13.287712379549449f / 32.0f)

// ---------------------------------------------------------------------------
// fp32 -> bf16: x -> xb, wq|wk|wv -> wqkvb, wp -> wpb.
// ---------------------------------------------------------------------------
__global__ __launch_bounds__(256) void convert_all(
    const float* __restrict__ x,  const float* __restrict__ wq,
    const float* __restrict__ wk, const float* __restrict__ wv,
    const float* __restrict__ wp,
    unsigned short* __restrict__ xb, unsigned short* __restrict__ wqkvb,
    unsigned short* __restrict__ wpb)
{
    const size_t XN = 2048u * 1024u, WN = 1024u * 1024u;
    size_t e = ((size_t)blockIdx.x * 256 + threadIdx.x) * 4;
    const float* s; unsigned short* d;
    if (e < XN)                { s = x  + e;               d = xb    + e; }
    else if (e < XN + WN)      { s = wq + (e - XN);        d = wqkvb + (e - XN); }
    else if (e < XN + 2 * WN)  { s = wk + (e - XN - WN);   d = wqkvb + (e - XN); }
    else if (e < XN + 3 * WN)  { s = wv + (e - XN - 2*WN); d = wqkvb + (e - XN); }
    else                       { s = wp + (e - XN - 3*WN); d = wpb   + (e - XN - 3*WN); }
    float4 v = *(const float4*)s;
    ushort4 o;
    o.x = f2bf(v.x); o.y = f2bf(v.y); o.z = f2bf(v.z); o.w = f2bf(v.w);
    *(ushort4*)d = o;
}

// ---------------------------------------------------------------------------
// bf16 GEMM (m97 structure, BK=64): C = A[M x 1024] * B[N x 1024]^T.
// BM x BN tile, 4 waves (2x2), wave tile (BM/2)x(BN/2), global_load_lds.
// 1D grid, XCD-aware decode (R11, neutral-to-slightly-positive; kept):
//   bx = (bid&7)*CX + (bid>>3)%CX ; by = (bid>>3)/CX ; CX = GX/8.
//
// *** RoPE binding order IS CORRECT AS WRITTEN — do not "fix" it. ***
// __sincosf(ang,&c,&s) binds c=sin(ang), s=cos(ang); the update is
// R(theta - pi/2) — reference rotation composed with a CONSTANT 90-degree
// rotation. Applied identically to q and k, the relative rotation
// R(th_n - th_m) (all logits see) matches the reference exactly.
// Binding sin-first gives the INVERSE relative rotation (R4 fail, 2.9e-2).
//
// Q-prescale: q section (n0<1024) scaled by 0.125 = 2^-3 (exact in bf16 ->
// attn exp argument BIT-IDENTICAL); removes *0.125f from attn hot loop.
// (R9/R10: transposed-V epilogue FAILED twice (2e-3/5e-3) — abandoned.)
//
// NOTE (R3): 128x128 tile at this shape starves the grid (384 blocks,
// occ 7.3%, 57us) — 64x128 (768 blocks) is right here.
// ---------------------------------------------------------------------------
template<int BM, int BN, int C32, int ROPE, int GX>
__global__ __launch_bounds__(256) void gemm_mfma(
    const unsigned short* __restrict__ A,
    const unsigned short* __restrict__ B,
    void* __restrict__ C, int Ntot)
{
    constexpr int MT = BM / 32, NT = BN / 32;
    constexpr int CX = GX / 8;
    __shared__ unsigned short As[BM * 64];
    __shared__ unsigned short Bs[BN * 64];

    const int bid  = blockIdx.x;
    const int bx   = (bid & 7) * CX + ((bid >> 3) % CX);
    const int by   = (bid >> 3) / CX;

    const int tid  = threadIdx.x;
    const int wave = tid >> 6, lane = tid & 63;
    const int l16  = lane & 15, quad = lane >> 4;
    const int m0   = by * BM, n0 = bx * BN;
    const int wm   = (wave & 1) * (BM / 2), wn = (wave >> 1) * (BN / 2);

    const int srow8 = lane >> 3;        // 0..7
    const int scol  = (lane & 7) * 8;   // 0..56

    f32x4 acc[MT][NT] = {};

    for (int k0 = 0; k0 < 1024; k0 += 64) {
        #pragma unroll
        for (int i = 0; i < BM / 32; i++) {
            int j = wave * (BM / 32) + i;
            async16(A + (size_t)(m0 + j * 8 + srow8) * 1024 + k0 + scol, &As[j * 512]);
        }
        #pragma unroll
        for (int i = 0; i < BN / 32; i++) {
            int j = wave * (BN / 32) + i;
            async16(B + (size_t)(n0 + j * 8 + srow8) * 1024 + k0 + scol, &Bs[j * 512]);
        }
        __syncthreads();

        #pragma unroll
        for (int ks = 0; ks < 2; ks++) {
            s16x8 af[MT], bfr[NT];
            #pragma unroll
            for (int mt = 0; mt < MT; mt++)
                af[mt] = *(const s16x8*)&As[(wm + mt * 16 + l16) * 64 + ks * 32 + quad * 8];
            #pragma unroll
            for (int nt = 0; nt < NT; nt++)
                bfr[nt] = *(const s16x8*)&Bs[(wn + nt * 16 + l16) * 64 + ks * 32 + quad * 8];
            #pragma unroll
            for (int mt = 0; mt < MT; mt++)
                #pragma unroll
                for (int nt = 0; nt < NT; nt++)
                    acc[mt][nt] = mfma16(af[mt], bfr[nt], acc[mt][nt]);
        }
        __syncthreads();
    }

    // Fused RoPE on q/k sections (in-register, fp32, before bf16 store)
    if constexpr (ROPE) {
        if (n0 < 2048) {
            const float sc = (n0 < 1024) ? 0.125f : 1.0f;   // Q-prescale
            #pragma unroll
            for (int mt = 0; mt < MT; mt++)
                #pragma unroll
                for (int r = 0; r < 4; r++) {
                    int m = m0 + wm + mt * 16 + quad * 4 + r;   // token
                    #pragma unroll
                    for (int nt = 0; nt < 2; nt++) {
                        int i = nt * 16 + l16;                  // 0..31 in head
                        float ang = (float)m * exp2f((float)i * ROPE_C);
                        float c, s;
                        __sincosf(ang, &c, &s);   // c=sin, s=cos — see header note
                        c *= sc; s *= sc;
                        float e0 = acc[mt][nt][r], e1 = acc[mt][nt + 2][r];
                        acc[mt][nt][r]     = e0 * c + e1 * s;
                        acc[mt][nt + 2][r] = e1 * c - e0 * s;
                    }
                }
        }
    }

    // C/D layout: col = lane&15, row = quad*4 + reg
    #pragma unroll
    for (int mt = 0; mt < MT; mt++)
        #pragma unroll
        for (int nt = 0; nt < NT; nt++)
            #pragma unroll
            for (int r = 0; r < 4; r++) {
                int m = m0 + wm + mt * 16 + quad * 4 + r;
                int n = n0 + wn + nt * 16 + l16;
                size_t idx = (size_t)m * Ntot + n;
                if (C32) ((float*)C)[idx] = acc[mt][nt][r];
                else     ((unsigned short*)C)[idx] = f2bf(acc[mt][nt][r]);
            }
}

// ---------------------------------------------------------------------------
// Split-K flash attention, 32x32x16 MFMA, operand-swapped QK (verified r12).
// 1024 blocks, XCD-swizzled 1D grid (R8-proven): 16 q-blocks sharing one
// (head,ksplit) slice -> same XCD -> per-XCD L2 working set ~1MB << 4MB.
//
// R12: K staged via global_load_lds (async DMA — cannot be sunk, unlike
// R7's reg loads), double-buffered Ks[2][64][64] (linear dest as DMA
// requires). Bank conflicts handled by the m201-proven rule-#21 pattern:
// per-lane GLOBAL source chunk pre-XOR'd ((l&7)^(l>>3), row&7 == l>>3),
// reads XOR the same: LDS chunk s of row r holds global chunk s^(r&7);
// read of global chunk c*2+half hits LDS chunk (c*2+half)^(row&7). XOR is
// an involution -> exact. V staging UNCHANGED (R8-proven gather into
// pad-72 Vt) — isolates the DMA+swizzle mechanism R9 left untested.
// Schedule: V-gather(t) -> mid-barrier (drains V loads; t=0 also drains
// K-DMA(0)) -> issue K-DMA(t+1) -> compute(t) -> end-barrier (its implicit
// vmcnt(0) drains the K-DMA; also releases Vt for t+1's gather).
// K-DMA(t+1) thus overlaps the entire compute(t) phase.
//
// P never touches LDS (T12): pack RNE pairs, v_permlane32_swap_b32
// (dst[32:63]<->src[0:31]): swap(lo,hi) -> lo'=word0/1, hi'=word2/3.
// Conversion must stay f2bf RNE (cvt_pk truncates -> 8e-3 bias, R2 fail).
// Q pre-scaled by 0.125 in qkv GEMM. T5 setprio kept (R11, neutral).
// ---------------------------------------------------------------------------
__global__ __launch_bounds__(256, 4) void attn_part(
    const unsigned short* __restrict__ qkv,
    unsigned short* __restrict__ Opart, float* __restrict__ Lpart)
{
    const int bid    = blockIdx.x;
    const int member = (bid >> 3) & 15;
    const int slice  = (bid & 7) + 8 * (bid >> 7);
    const int h  = slice & 15;
    const int ks = slice >> 4;
    const int q0 = member * 128;

    const int tid  = threadIdx.x;
    const int wave = tid >> 6, lane = tid & 63;
    const int l32  = lane & 31, half = lane >> 5;

    __shared__ unsigned short Ks[2][64][64];   // [buf][key][chunk-swizzled d]
    __shared__ unsigned short Vt[64][72];      // [d][key] pad-72 (unchanged)

    const int srow8 = lane >> 3;                 // 0..7
    const int csw   = ((lane & 7) ^ srow8) * 8;  // pre-swizzled source chunk

    auto stageK = [&](int t, int p) {
        const int kt = ks * 512 + t * 64;
        #pragma unroll
        for (int i = 0; i < 2; i++) {
            int rb = wave * 2 + i;               // row-block 0..7
            async16(qkv + (size_t)(kt + rb * 8 + srow8) * 3072 + 1024 + h * 64 + csw,
                    &Ks[p][rb * 8][0]);
        }
    };

    stageK(0, 0);                                // in flight under Q loads

    const unsigned short* qp = qkv + (size_t)(q0 + wave * 32 + l32) * 3072 + h * 64 + half * 8;
    s16x8 qb[4];
    #pragma unroll
    for (int c = 0; c < 4; c++)
        qb[c] = *(const s16x8*)(qp + c * 16);

    f32x16 o0 = {}, o1 = {};
    float lsum = 0.f;

    for (int t = 0; t < 8; t++) {
        const int p = t & 1;
        const int kt = ks * 512 + t * 64;

        if (tid < 128) {                         // V gather (R8-proven, unchanged)
            int g  = tid & 15;
            int d0 = (tid >> 4) * 8;
            const unsigned short* gv = qkv + (size_t)(kt + 4 * g) * 3072 + 2048 + h * 64 + d0;
            unsigned short a0[8], a1[8], a2[8], a3[8];
            *(uint4*)a0 = *(const uint4*)gv;
            *(uint4*)a1 = *(const uint4*)(gv + 3072);
            *(uint4*)a2 = *(const uint4*)(gv + 6144);
            *(uint4*)a3 = *(const uint4*)(gv + 9216);
            #pragma unroll
            for (int d = 0; d < 8; d++) {
                ushort4 w;
                w.x = a0[d]; w.y = a1[d]; w.z = a2[d]; w.w = a3[d];
                *(ushort4*)&Vt[d0 + d][4 * g] = w;
            }
        }
        __syncthreads();   // Vt(t) ready; K-DMA(t) drained here (t=0) or at prior end-barrier

        if (t < 7) stageK(t + 1, p ^ 1);         // async DMA overlaps compute(t)

        #pragma unroll
        for (int g = 0; g < 2; g++) {
            f32x16 s = {};
            __builtin_amdgcn_s_setprio(1);
            #pragma unroll
            for (int c = 0; c < 4; c++) {
                int row = g * 32 + l32;
                int ch  = ((c * 2 + half) ^ (row & 7)) * 8;   // swizzled read
                s16x8 ka = *(const s16x8*)&Ks[p][row][ch];
                s = mfma32(ka, qb[c], s);
            }
            __builtin_amdgcn_s_setprio(0);
            #pragma unroll
            for (int f = 0; f < 2; f++) {
                float e[8];
                #pragma unroll
                for (int j = 0; j < 8; j++) {
                    e[j] = __expf(s[8 * f + j]);   // scale folded into Q
                    lsum += e[j];
                }
                // RNE-packed pairs (bit-identical P to LDS baseline)
                unsigned w0 = pack2bf(e[0], e[1]);   // lo0
                unsigned w1 = pack2bf(e[2], e[3]);   // lo1
                unsigned w2 = pack2bf(e[4], e[5]);   // hi0
                unsigned w3 = pack2bf(e[6], e[7]);   // hi1
                // DST=lo, SRC=hi: dst'=word0/1, src'=word2/3
                asm("v_permlane32_swap_b32 %0, %1" : "+v"(w0), "+v"(w2));
                asm("v_permlane32_swap_b32 %0, %1" : "+v"(w1), "+v"(w3));
                u32x4 wv; wv.x = w0; wv.y = w1; wv.z = w2; wv.w = w3;
                s16x8 pa = __builtin_bit_cast(s16x8, wv);
                const int c = 2 * g + f;
                s16x8 v0 = *(const s16x8*)&Vt[l32][c * 16 + half * 8];
                s16x8 v1 = *(const s16x8*)&Vt[32 + l32][c * 16 + half * 8];
                __builtin_amdgcn_s_setprio(1);
                o0 = mfma32(pa, v0, o0);
                o1 = mfma32(pa, v1, o1);
                __builtin_amdgcn_s_setprio(0);
            }
        }
        __syncthreads();   // drains K-DMA(t+1); releases Vt for next gather
    }

    lsum += __shfl_xor(lsum, 32, 64);

    const int mq = q0 + wave * 32;
    unsigned short* opBase = Opart + (size_t)ks * 2048 * 1024;
    #pragma unroll
    for (int r = 0; r < 16; r++) {
        int qr = (r & 3) + 8 * (r >> 2) + 4 * half;
        unsigned short* op = opBase + (size_t)(mq + qr) * 1024 + h * 64;
        op[l32]      = f2bf(o0[r]);
        op[32 + l32] = f2bf(o1[r]);
    }
    if (half == 0)
        Lpart[((size_t)ks * 2048 + mq + l32) * 16 + h] = lsum;
}

// ---------------------------------------------------------------------------
// Combine 4 bf16 split-K partials: ab = (sum n_i) / (sum l_i), bf16.
// ---------------------------------------------------------------------------
__global__ __launch_bounds__(256) void combine(
    const unsigned short* __restrict__ Opart, const float* __restrict__ Lpart,
    unsigned short* __restrict__ ab)
{
    size_t e = ((size_t)blockIdx.x * 256 + threadIdx.x) * 4;
    int tok = (int)(e >> 10);
    int h = (int)((e & 1023) >> 6);
    float l = 0.f;
    #pragma unroll
    for (int s = 0; s < 4; s++)
        l += Lpart[((size_t)s * 2048 + tok) * 16 + h];
    float inv = 1.0f / l;
    float a0 = 0.f, a1 = 0.f, a2 = 0.f, a3 = 0.f;
    #pragma unroll
    for (int s = 0; s < 4; s++) {
        ushort4 n = *(const ushort4*)(Opart + (size_t)s * 2048 * 1024 + e);
        a0 += bf2f(n.x); a1 += bf2f(n.y); a2 += bf2f(n.z); a3 += bf2f(n.w);
    }
    ushort4 w;
    w.x = f2bf(a0 * inv);
    w.y = f2bf(a1 * inv);
    w.z = f2bf(a2 * inv);
    w.w = f2bf(a3 * inv);
    *(ushort4*)(ab + e) = w;
}

extern "C" void kernel_launch(void* const* d_in, const int* in_sizes, int n_in,
                              void* d_out, int out_size, void* d_ws, size_t ws_size,
                              hipStream_t stream)
{
    const float* x  = (const float*)d_in[0];
    const float* wq = (const float*)d_in[1];
    const float* wk = (const float*)d_in[2];
    const float* wv = (const float*)d_in[3];
    const float* wp = (const float*)d_in[4];

    unsigned short* xb    = (unsigned short*)d_ws;        // 2M shorts
    unsigned short* wqkvb = xb    + 2u * 1024 * 1024;     // 3M
    unsigned short* wpb   = wqkvb + 3u * 1024 * 1024;     // 1M
    unsigned short* qkv   = wpb   + 1u * 1024 * 1024;     // 6M
    unsigned short* ab    = qkv   + 2048u * 3072;         // 2M
    unsigned short* Opart = ab    + 2u * 1024 * 1024;     // 4 x 2048 x 1024 bf16
    float* Lpart = (float*)(Opart + 4u * 2048 * 1024);    // 4 x 2048 x 16 fp32

    convert_all<<<6144, 256, 0, stream>>>(x, wq, wk, wv, wp, xb, wqkvb, wpb);
    // qkv GEMM with fused RoPE: 64x128 tile, 1D XCD-swizzled grid of 768
    gemm_mfma<64, 128, 0, 1, 24><<<768, 256, 0, stream>>>(
        xb, wqkvb, qkv, 3072);
    // attn: 1D XCD-swizzled grid, K via swizzled-source DMA dbuf
    attn_part<<<1024, 256, 0, stream>>>(qkv, Opart, Lpart);
    combine<<<2048, 256, 0, stream>>>(Opart, Lpart, ab);
    // proj: 64x64 tile, 1D XCD-swizzled grid of 512, fp32 out
    gemm_mfma<64, 64, 1, 0, 16><<<512, 256, 0, stream>>>(
        ab, wpb, d_out, 1024);
}

// Round 14
// 149.476 us; speedup vs baseline: 1.0138x; 1.0056x over previous
//
#include <hip/hip_runtime.h>

typedef short s16x8 __attribute__((ext_vector_type(8)));
typedef float f32x4 __attribute__((ext_vector_type(4)));
typedef float f32x16 __attribute__((ext_vector_type(16)));
typedef unsigned int u32x4 __attribute__((ext_vector_type(4)));

__device__ __forceinline__ unsigned short f2bf(float f) {
    unsigned int u = __float_as_uint(f);
    u += 0x7fff + ((u >> 16) & 1);   // RNE
    return (unsigned short)(u >> 16);
}
__device__ __forceinline__ float bf2f(unsigned short h) {
    return __uint_as_float(((unsigned int)h) << 16);
}
__device__ __forceinline__ unsigned pack2bf(float lo, float hi) {
    return (unsigned)f2bf(lo) | ((unsigned)f2bf(hi) << 16);   // RNE both halves
}
__device__ __forceinline__ f32x4 mfma16(s16x8 a, s16x8 b, f32x4 c) {
    return __builtin_amdgcn_mfma_f32_16x16x32_bf16(a, b, c, 0, 0, 0);
}
__device__ __forceinline__ f32x16 mfma32(s16x8 a, s16x8 b, f32x16 c) {
    return __builtin_amdgcn_mfma_f32_32x32x16_bf16(a, b, c, 0, 0, 0);
}
__device__ __forceinline__ void async16(const void* g, void* l) {
    __builtin_amdgcn_global_load_lds(
        (const __attribute__((address_space(1))) void*)g,
        (__attribute__((address_space(3))) void*)l, 16, 0, 0);
}

#define ROPE_C (-13.287712379549449f / 32.0f)

// ---------------------------------------------------------------------------
// fp32 -> bf16: x -> xb, wq|wk|wv -> wqkvb, wp -> wpb.
// ---------------------------------------------------------------------------
__global__ __launch_bounds__(256) void convert_all(
    const float* __restrict__ x,  const float* __restrict__ wq,
    const float* __restrict__ wk, const float* __restrict__ wv,
    const float* __restrict__ wp,
    unsigned short* __restrict__ xb, unsigned short* __restrict__ wqkvb,
    unsigned short* __restrict__ wpb)
{
    const size_t XN = 2048u * 1024u, WN = 1024u * 1024u;
    size_t e = ((size_t)blockIdx.x * 256 + threadIdx.x) * 4;
    const float* s; unsigned short* d;
    if (e < XN)                { s = x  + e;               d = xb    + e; }
    else if (e < XN + WN)      { s = wq + (e - XN);        d = wqkvb + (e - XN); }
    else if (e < XN + 2 * WN)  { s = wk + (e - XN - WN);   d = wqkvb + (e - XN); }
    else if (e < XN + 3 * WN)  { s = wv + (e - XN - 2*WN); d = wqkvb + (e - XN); }
    else                       { s = wp + (e - XN - 3*WN); d = wpb   + (e - XN - 3*WN); }
    float4 v = *(const float4*)s;
    ushort4 o;
    o.x = f2bf(v.x); o.y = f2bf(v.y); o.z = f2bf(v.z); o.w = f2bf(v.w);
    *(ushort4*)d = o;
}

// ---------------------------------------------------------------------------
// bf16 GEMM (m97 structure, BK=64): C = A[M x 1024] * B[N x 1024]^T.
// BM x BN tile, 4 waves (2x2), wave tile (BM/2)x(BN/2), global_load_lds.
// 1D grid, XCD-aware decode (R11, neutral; kept):
//   bx = (bid&7)*CX + (bid>>3)%CX ; by = (bid>>3)/CX ; CX = GX/8.
//
// *** RoPE binding order IS CORRECT AS WRITTEN — do not "fix" it. ***
// __sincosf(ang,&c,&s) binds c=sin(ang), s=cos(ang); the update is
// R(theta - pi/2) — reference rotation composed with a CONSTANT 90-degree
// rotation. Applied identically to q and k, the relative rotation
// R(th_n - th_m) (all logits see) matches the reference exactly.
// Binding sin-first gives the INVERSE relative rotation (R4 fail, 2.9e-2).
//
// Q-prescale: q section (n0<1024) scaled by 0.125 = 2^-3 (exact in bf16 ->
// attn exp argument BIT-IDENTICAL); removes *0.125f from attn hot loop.
// (R9/R10: transposed-V epilogue FAILED twice (2e-3/5e-3) — abandoned.
//  R12 exonerated DMA+source-swizzle, so the VT epilogue itself was bad.)
//
// NOTE (R3): 128x128 tile at this shape starves the grid (384 blocks,
// occ 7.3%, 57us) — 64x128 (768 blocks) is right here.
// ---------------------------------------------------------------------------
template<int BM, int BN, int C32, int ROPE, int GX>
__global__ __launch_bounds__(256) void gemm_mfma(
    const unsigned short* __restrict__ A,
    const unsigned short* __restrict__ B,
    void* __restrict__ C, int Ntot)
{
    constexpr int MT = BM / 32, NT = BN / 32;
    constexpr int CX = GX / 8;
    __shared__ unsigned short As[BM * 64];
    __shared__ unsigned short Bs[BN * 64];

    const int bid  = blockIdx.x;
    const int bx   = (bid & 7) * CX + ((bid >> 3) % CX);
    const int by   = (bid >> 3) / CX;

    const int tid  = threadIdx.x;
    const int wave = tid >> 6, lane = tid & 63;
    const int l16  = lane & 15, quad = lane >> 4;
    const int m0   = by * BM, n0 = bx * BN;
    const int wm   = (wave & 1) * (BM / 2), wn = (wave >> 1) * (BN / 2);

    const int srow8 = lane >> 3;        // 0..7
    const int scol  = (lane & 7) * 8;   // 0..56

    f32x4 acc[MT][NT] = {};

    for (int k0 = 0; k0 < 1024; k0 += 64) {
        #pragma unroll
        for (int i = 0; i < BM / 32; i++) {
            int j = wave * (BM / 32) + i;
            async16(A + (size_t)(m0 + j * 8 + srow8) * 1024 + k0 + scol, &As[j * 512]);
        }
        #pragma unroll
        for (int i = 0; i < BN / 32; i++) {
            int j = wave * (BN / 32) + i;
            async16(B + (size_t)(n0 + j * 8 + srow8) * 1024 + k0 + scol, &Bs[j * 512]);
        }
        __syncthreads();

        #pragma unroll
        for (int ks = 0; ks < 2; ks++) {
            s16x8 af[MT], bfr[NT];
            #pragma unroll
            for (int mt = 0; mt < MT; mt++)
                af[mt] = *(const s16x8*)&As[(wm + mt * 16 + l16) * 64 + ks * 32 + quad * 8];
            #pragma unroll
            for (int nt = 0; nt < NT; nt++)
                bfr[nt] = *(const s16x8*)&Bs[(wn + nt * 16 + l16) * 64 + ks * 32 + quad * 8];
            #pragma unroll
            for (int mt = 0; mt < MT; mt++)
                #pragma unroll
                for (int nt = 0; nt < NT; nt++)
                    acc[mt][nt] = mfma16(af[mt], bfr[nt], acc[mt][nt]);
        }
        __syncthreads();
    }

    // Fused RoPE on q/k sections (in-register, fp32, before bf16 store)
    if constexpr (ROPE) {
        if (n0 < 2048) {
            const float sc = (n0 < 1024) ? 0.125f : 1.0f;   // Q-prescale
            #pragma unroll
            for (int mt = 0; mt < MT; mt++)
                #pragma unroll
                for (int r = 0; r < 4; r++) {
                    int m = m0 + wm + mt * 16 + quad * 4 + r;   // token
                    #pragma unroll
                    for (int nt = 0; nt < 2; nt++) {
                        int i = nt * 16 + l16;                  // 0..31 in head
                        float ang = (float)m * exp2f((float)i * ROPE_C);
                        float c, s;
                        __sincosf(ang, &c, &s);   // c=sin, s=cos — see header note
                        c *= sc; s *= sc;
                        float e0 = acc[mt][nt][r], e1 = acc[mt][nt + 2][r];
                        acc[mt][nt][r]     = e0 * c + e1 * s;
                        acc[mt][nt + 2][r] = e1 * c - e0 * s;
                    }
                }
        }
    }

    // C/D layout: col = lane&15, row = quad*4 + reg
    #pragma unroll
    for (int mt = 0; mt < MT; mt++)
        #pragma unroll
        for (int nt = 0; nt < NT; nt++)
            #pragma unroll
            for (int r = 0; r < 4; r++) {
                int m = m0 + wm + mt * 16 + quad * 4 + r;
                int n = n0 + wn + nt * 16 + l16;
                size_t idx = (size_t)m * Ntot + n;
                if (C32) ((float*)C)[idx] = acc[mt][nt][r];
                else     ((unsigned short*)C)[idx] = f2bf(acc[mt][nt][r]);
            }
}

// ---------------------------------------------------------------------------
// Split-K flash attention, 32x32x16 MFMA, operand-swapped QK (verified r12).
// 1024 blocks, XCD-swizzled 1D grid (R8-proven): 16 q-blocks sharing one
// (head,ksplit) slice -> same XCD -> per-XCD L2 working set ~1MB << 4MB.
//
// K staged via global_load_lds (R12-proven: async DMA, double-buffered,
// linear dest + pre-swizzled GLOBAL source chunk (l&7)^(l>>3), reads XOR
// the same — rule #21, bit-exact).
//
// R13: V-gather latency hidden (T14 with the forcing R7 lacked):
//   issue V-loads(t+1) into regs BEFORE compute(t), pinned by
//   sched_barrier(0) (prevents the compiler sinking them into the commit —
//   R7's failure mode); commit to Vt AFTER barrier A (A's implicit vmcnt(0)
//   drain means the commit needs no extra wait). Gather rebalanced across
//   all 256 threads (2 keys each; waves 2-3 were idle since K went DMA).
//   Barrier count unchanged (2/t-step), LDS unchanged (4 blocks/CU).
// Race audit: compute(t) reads Ks[p],Vt; stageK(t+1) writes Ks[p^1]
// (disjoint); V-commit(t+1) happens after barrier A (all waves done
// reading Vt(t)); barrier B publishes Vt(t+1) before compute(t+1).
//
// P never touches LDS (T12): pack RNE pairs, v_permlane32_swap_b32
// (dst[32:63]<->src[0:31]): swap(lo,hi) -> lo'=word0/1, hi'=word2/3.
// Conversion must stay f2bf RNE (cvt_pk truncates -> 8e-3 bias, R2 fail).
// Q pre-scaled by 0.125 in qkv GEMM. T5 setprio kept (neutral, R11).
// ---------------------------------------------------------------------------
__global__ __launch_bounds__(256, 4) void attn_part(
    const unsigned short* __restrict__ qkv,
    unsigned short* __restrict__ Opart, float* __restrict__ Lpart)
{
    const int bid    = blockIdx.x;
    const int member = (bid >> 3) & 15;
    const int slice  = (bid & 7) + 8 * (bid >> 7);
    const int h  = slice & 15;
    const int ks = slice >> 4;
    const int q0 = member * 128;

    const int tid  = threadIdx.x;
    const int wave = tid >> 6, lane = tid & 63;
    const int l32  = lane & 31, half = lane >> 5;

    __shared__ unsigned short Ks[2][64][64];   // [buf][key][chunk-swizzled d]
    __shared__ unsigned short Vt[64][72];      // [d][key] pad-72

    const int srow8 = lane >> 3;                 // 0..7
    const int csw   = ((lane & 7) ^ srow8) * 8;  // pre-swizzled source chunk

    auto stageK = [&](int t, int p) {
        const int kt = ks * 512 + t * 64;
        #pragma unroll
        for (int i = 0; i < 2; i++) {
            int rb = wave * 2 + i;               // row-block 0..7
            async16(qkv + (size_t)(kt + rb * 8 + srow8) * 3072 + 1024 + h * 64 + csw,
                    &Ks[p][rb * 8][0]);
        }
    };

    // V gather across all 256 threads: 2 keys x 8 d-elements each
    const int vg  = tid & 31;                    // key-pair index (keys 2vg, 2vg+1)
    const int vd0 = (tid >> 5) * 8;              // 8-d block
    uint4 vr0, vr1;
    auto issueV = [&](int t) {
        const unsigned short* gv = qkv + (size_t)(ks * 512 + t * 64 + 2 * vg) * 3072
                                       + 2048 + h * 64 + vd0;
        vr0 = *(const uint4*)gv;
        vr1 = *(const uint4*)(gv + 3072);
    };
    auto commitV = [&]() {
        unsigned short a0[8], a1[8];
        *(uint4*)a0 = vr0; *(uint4*)a1 = vr1;
        #pragma unroll
        for (int d = 0; d < 8; d++) {
            ushort2 w; w.x = a0[d]; w.y = a1[d];
            *(ushort2*)&Vt[vd0 + d][2 * vg] = w;  // 2-way bank alias (free, m136)
        }
    };

    stageK(0, 0);                                // K-DMA(0) in flight
    issueV(0);

    const unsigned short* qp = qkv + (size_t)(q0 + wave * 32 + l32) * 3072 + h * 64 + half * 8;
    s16x8 qb[4];
    #pragma unroll
    for (int c = 0; c < 4; c++)
        qb[c] = *(const s16x8*)(qp + c * 16);

    commitV();                                   // auto-waits V(0) loads
    f32x16 o0 = {}, o1 = {};
    float lsum = 0.f;

    __syncthreads();                             // Ks[0] + Vt(0) ready

    for (int t = 0; t < 8; t++) {
        const int p = t & 1;
        if (t < 7) {
            stageK(t + 1, p ^ 1);                // async DMA under compute(t)
            issueV(t + 1);                       // reg loads under compute(t)
            __builtin_amdgcn_sched_barrier(0);   // pin: no sinking past here
        }

        #pragma unroll
        for (int g = 0; g < 2; g++) {
            f32x16 s = {};
            __builtin_amdgcn_s_setprio(1);
            #pragma unroll
            for (int c = 0; c < 4; c++) {
                int row = g * 32 + l32;
                int ch  = ((c * 2 + half) ^ (row & 7)) * 8;   // swizzled read
                s16x8 ka = *(const s16x8*)&Ks[p][row][ch];
                s = mfma32(ka, qb[c], s);
            }
            __builtin_amdgcn_s_setprio(0);
            #pragma unroll
            for (int f = 0; f < 2; f++) {
                float e[8];
                #pragma unroll
                for (int j = 0; j < 8; j++) {
                    e[j] = __expf(s[8 * f + j]);   // scale folded into Q
                    lsum += e[j];
                }
                // RNE-packed pairs (bit-identical P to LDS baseline)
                unsigned w0 = pack2bf(e[0], e[1]);   // lo0
                unsigned w1 = pack2bf(e[2], e[3]);   // lo1
                unsigned w2 = pack2bf(e[4], e[5]);   // hi0
                unsigned w3 = pack2bf(e[6], e[7]);   // hi1
                // DST=lo, SRC=hi: dst'=word0/1, src'=word2/3
                asm("v_permlane32_swap_b32 %0, %1" : "+v"(w0), "+v"(w2));
                asm("v_permlane32_swap_b32 %0, %1" : "+v"(w1), "+v"(w3));
                u32x4 wv; wv.x = w0; wv.y = w1; wv.z = w2; wv.w = w3;
                s16x8 pa = __builtin_bit_cast(s16x8, wv);
                const int c = 2 * g + f;
                s16x8 v0 = *(const s16x8*)&Vt[l32][c * 16 + half * 8];
                s16x8 v1 = *(const s16x8*)&Vt[32 + l32][c * 16 + half * 8];
                __builtin_amdgcn_s_setprio(1);
                o0 = mfma32(pa, v0, o0);
                o1 = mfma32(pa, v1, o1);
                __builtin_amdgcn_s_setprio(0);
            }
        }

        __syncthreads();          // (A) all read Vt(t); drains K-DMA + V-loads
        if (t < 7) {
            commitV();            // Vt(t+1), no extra wait needed
            __syncthreads();      // (B) Vt(t+1) visible to all
        }
    }

    lsum += __shfl_xor(lsum, 32, 64);

    const int mq = q0 + wave * 32;
    unsigned short* opBase = Opart + (size_t)ks * 2048 * 1024;
    #pragma unroll
    for (int r = 0; r < 16; r++) {
        int qr = (r & 3) + 8 * (r >> 2) + 4 * half;
        unsigned short* op = opBase + (size_t)(mq + qr) * 1024 + h * 64;
        op[l32]      = f2bf(o0[r]);
        op[32 + l32] = f2bf(o1[r]);
    }
    if (half == 0)
        Lpart[((size_t)ks * 2048 + mq + l32) * 16 + h] = lsum;
}

// ---------------------------------------------------------------------------
// Combine 4 bf16 split-K partials: ab = (sum n_i) / (sum l_i), bf16.
// ---------------------------------------------------------------------------
__global__ __launch_bounds__(256) void combine(
    const unsigned short* __restrict__ Opart, const float* __restrict__ Lpart,
    unsigned short* __restrict__ ab)
{
    size_t e = ((size_t)blockIdx.x * 256 + threadIdx.x) * 4;
    int tok = (int)(e >> 10);
    int h = (int)((e & 1023) >> 6);
    float l = 0.f;
    #pragma unroll
    for (int s = 0; s < 4; s++)
        l += Lpart[((size_t)s * 2048 + tok) * 16 + h];
    float inv = 1.0f / l;
    float a0 = 0.f, a1 = 0.f, a2 = 0.f, a3 = 0.f;
    #pragma unroll
    for (int s = 0; s < 4; s++) {
        ushort4 n = *(const ushort4*)(Opart + (size_t)s * 2048 * 1024 + e);
        a0 += bf2f(n.x); a1 += bf2f(n.y); a2 += bf2f(n.z); a3 += bf2f(n.w);
    }
    ushort4 w;
    w.x = f2bf(a0 * inv);
    w.y = f2bf(a1 * inv);
    w.z = f2bf(a2 * inv);
    w.w = f2bf(a3 * inv);
    *(ushort4*)(ab + e) = w;
}

extern "C" void kernel_launch(void* const* d_in, const int* in_sizes, int n_in,
                              void* d_out, int out_size, void* d_ws, size_t ws_size,
                              hipStream_t stream)
{
    const float* x  = (const float*)d_in[0];
    const float* wq = (const float*)d_in[1];
    const float* wk = (const float*)d_in[2];
    const float* wv = (const float*)d_in[3];
    const float* wp = (const float*)d_in[4];

    unsigned short* xb    = (unsigned short*)d_ws;        // 2M shorts
    unsigned short* wqkvb = xb    + 2u * 1024 * 1024;     // 3M
    unsigned short* wpb   = wqkvb + 3u * 1024 * 1024;     // 1M
    unsigned short* qkv   = wpb   + 1u * 1024 * 1024;     // 6M
    unsigned short* ab    = qkv   + 2048u * 3072;         // 2M
    unsigned short* Opart = ab    + 2u * 1024 * 1024;     // 4 x 2048 x 1024 bf16
    float* Lpart = (float*)(Opart + 4u * 2048 * 1024);    // 4 x 2048 x 16 fp32

    convert_all<<<6144, 256, 0, stream>>>(x, wq, wk, wv, wp, xb, wqkvb, wpb);
    // qkv GEMM with fused RoPE: 64x128 tile, 1D XCD-swizzled grid of 768
    gemm_mfma<64, 128, 0, 1, 24><<<768, 256, 0, stream>>>(
        xb, wqkvb, qkv, 3072);
    // attn: 1D XCD-swizzled grid; K via swizzled-source DMA dbuf,
    // V via prefetched reg-gather (sched_barrier-pinned)
    attn_part<<<1024, 256, 0, stream>>>(qkv, Opart, Lpart);
    combine<<<2048, 256, 0, stream>>>(Opart, Lpart, ab);
    // proj: 64x64 tile, 1D XCD-swizzled grid of 512, fp32 out
    gemm_mfma<64, 64, 1, 0, 16><<<512, 256, 0, stream>>>(
        ab, wpb, d_out, 1024);
}